// Round 5
// baseline (220.597 us; speedup 1.0000x reference)
//
#include <hip/hip_runtime.h>
#include <cmath>

namespace {
constexpr int NB  = 256;   // batch
constexpr int CI  = 64;    // in channels
constexpr int CO  = 64;    // out channels
constexpr int TT  = 64;    // time
constexpr int V   = 25;    // vertices
constexpr int REL = 8;     // rel channels
constexpr int TV  = TT * V;   // 1600
constexpr int CC  = 8;     // channels per fused block
constexpr int IP  = 26;    // inp row pad (8B-aligned rows for float2)
constexpr int AP  = 28;    // Af row pad (16B-aligned rows for float4)
}

// ---------------------------------------------------------------------------
// K1: per-n temporal reduction -> x1,x2 (REL*V each) into ws. (unchanged)
// ---------------------------------------------------------------------------
__global__ __launch_bounds__(1024) void k1_x12(
    const float* __restrict__ x,
    const float* __restrict__ w1, const float* __restrict__ b1,
    const float* __restrict__ w2, const float* __restrict__ b2,
    float* __restrict__ ws) {
  const int n = blockIdx.x;
  const int tid = threadIdx.x;
  __shared__ __align__(16) float xs[8][TV];
  __shared__ float xsum[CI][V];
  __shared__ float w12[2][REL][CI];

  for (int idx = tid; idx < 2 * REL * CI; idx += 1024) {
    int half = idx / (REL * CI), rem = idx % (REL * CI);
    w12[half][rem / CI][rem % CI] = half ? w2[rem] : w1[rem];
  }

  const float4* xb = reinterpret_cast<const float4*>(x + (size_t)n * (CI * TV));
  float4* xsv = reinterpret_cast<float4*>(&xs[0][0]);
  constexpr int V4G = 8 * TV / 4;  // 3200

  for (int g = 0; g < 8; ++g) {
    __syncthreads();
    for (int idx = tid; idx < V4G; idx += 1024)
      xsv[idx] = xb[g * V4G + idx];
    __syncthreads();
    if (tid < 8 * V) {
      int ch = tid / V, v = tid % V;
      float acc = 0.f;
      #pragma unroll
      for (int t = 0; t < TT; ++t) acc += xs[ch][t * V + v];
      xsum[g * 8 + ch][v] = acc;
    }
  }
  __syncthreads();

  if (tid < 2 * REL * V) {
    int half = tid / (REL * V), rem = tid % (REL * V);
    int r = rem / V, v = rem % V;
    float a = 0.f;
    #pragma unroll
    for (int i = 0; i < CI; ++i) a = fmaf(w12[half][r][i], xsum[i][v], a);
    ws[(size_t)n * (2 * REL * V) + tid] = a * (1.f / TT) + (half ? b2[r] : b1[r]);
  }
}

// ---------------------------------------------------------------------------
// K2 fused: per (n, 8-channel chunk):
//   P0: Af[8][25][AP] in LDS (tanh inline)
//   P1: inputs[8][64][IP] in LDS (400 threads own float4 tv-columns)
//   P2: out[c,t,u] = sum_v Af[c,u,v]*inp[c,t,v], inp rows in regs, direct store
// LDS total 77728 B -> 2 blocks/CU. No HBM intermediate.
// Grid (n, cb): same-n blocks share XCD -> x[n] fetched from HBM once.
// ---------------------------------------------------------------------------
__global__ __launch_bounds__(512, 4) void k2_fused(
    const float* __restrict__ x, const float* __restrict__ A,
    const float* __restrict__ w3, const float* __restrict__ b3,
    const float* __restrict__ wr, const float* __restrict__ br,
    const float* __restrict__ ws, float* __restrict__ out) {
  const int n   = blockIdx.x;        // 0..255
  const int cb  = blockIdx.y;        // 0..7
  const int c0  = cb * CC;
  const int tid = threadIdx.x;       // 0..511

  __shared__ __align__(16) float inp[CC * TT * IP];   // 53248 B
  __shared__ __align__(16) float Afs[CC * V * AP];    // 22400 B
  __shared__ __align__(16) float wrs[CI * CC + CC];   // 2080 B (wr^T chunk + br)

  // ---- P0a: stage wr^T chunk (+ br row)
  {
    int i = tid >> 3, cc = tid & 7;                   // tid < 512 == CI*CC
    wrs[i * CC + cc] = wr[(size_t)(c0 + cc) * CI + i];
    if (tid < CC) wrs[CI * CC + tid] = br[c0 + tid];
  }

  // ---- P0b: Af[cc][u][v] = A[u][v] + b3[c] + sum_r w3[c][r]*tanh(x1[r][u]-x2[r][v])
  const float* x1n = ws + (size_t)n * (2 * REL * V);
  const float* x2n = x1n + REL * V;
  for (int idx = tid; idx < V * V; idx += 512) {
    int u = idx / V, v = idx % V;
    float t8[REL];
    #pragma unroll
    for (int r = 0; r < REL; ++r)
      t8[r] = tanhf(x1n[r * V + u] - x2n[r * V + v]);
    const float base = A[idx];
    #pragma unroll
    for (int cc = 0; cc < CC; ++cc) {
      float acc = base + b3[c0 + cc];
      #pragma unroll
      for (int r = 0; r < REL; ++r)
        acc = fmaf(w3[(c0 + cc) * REL + r], t8[r], acc);
      Afs[(cc * V + u) * AP + v] = acc;
    }
  }
  __syncthreads();

  // ---- P1: inputs tile (all t) into LDS. 400 threads own float4 tv-columns.
  if (tid < TV / 4) {
    const float* xp = x + (size_t)n * (CI * TV) + tid * 4;
    float acc[CC][4];
    #pragma unroll
    for (int cc = 0; cc < CC; ++cc) {
      float b = wrs[CI * CC + cc];
      acc[cc][0] = b; acc[cc][1] = b; acc[cc][2] = b; acc[cc][3] = b;
    }
    #pragma unroll 4
    for (int i = 0; i < CI; ++i) {
      float4 xv = *reinterpret_cast<const float4*>(xp + (size_t)i * TV);
      float4 wa = *reinterpret_cast<const float4*>(&wrs[i * CC]);      // broadcast
      float4 wb = *reinterpret_cast<const float4*>(&wrs[i * CC + 4]);  // broadcast
      float w8[8] = {wa.x, wa.y, wa.z, wa.w, wb.x, wb.y, wb.z, wb.w};
      #pragma unroll
      for (int cc = 0; cc < CC; ++cc) {
        acc[cc][0] = fmaf(w8[cc], xv.x, acc[cc][0]);
        acc[cc][1] = fmaf(w8[cc], xv.y, acc[cc][1]);
        acc[cc][2] = fmaf(w8[cc], xv.z, acc[cc][2]);
        acc[cc][3] = fmaf(w8[cc], xv.w, acc[cc][3]);
      }
    }
    int tv0 = tid * 4;
    int t = tv0 / V, v = tv0 % V;
    #pragma unroll
    for (int k = 0; k < 4; ++k) {
      #pragma unroll
      for (int cc = 0; cc < CC; ++cc)
        inp[(cc * TT + t) * IP + v] = acc[cc][k];
      if (++v == V) { v = 0; ++t; }
    }
  }
  __syncthreads();

  // ---- P2: thread = (cc, t-pair, u-half); inp rows in regs, Af rows streamed
  const int cc = tid >> 6;            // 0..7
  const int tp = (tid >> 1) & 31;     // 0..31
  const int uh = tid & 1;             // 0..1
  const int t0 = tp * 2;
  const int ub = uh ? 13 : 0;
  const int uc = uh ? 12 : 13;

  float in[2][26];
  {
    const float2* r0 = reinterpret_cast<const float2*>(&inp[(cc * TT + t0) * IP]);
    const float2* r1 = reinterpret_cast<const float2*>(&inp[(cc * TT + t0 + 1) * IP]);
    #pragma unroll
    for (int h = 0; h < 13; ++h) {
      float2 a = r0[h], b = r1[h];
      in[0][2*h] = a.x; in[0][2*h+1] = a.y;
      in[1][2*h] = b.x; in[1][2*h+1] = b.y;
    }
  }

  const float* afbase = &Afs[cc * V * AP];
  float* ob = out + (((size_t)n * CO + (c0 + cc)) * TT + t0) * V;

  for (int ku = 0; ku < uc; ++ku) {
    const int u = ub + ku;
    const float4* ar = reinterpret_cast<const float4*>(afbase + u * AP);
    float av[25];
    #pragma unroll
    for (int g = 0; g < 6; ++g) {
      float4 q = ar[g];
      av[4*g] = q.x; av[4*g+1] = q.y; av[4*g+2] = q.z; av[4*g+3] = q.w;
    }
    av[24] = afbase[u * AP + 24];

    #pragma unroll
    for (int ti = 0; ti < 2; ++ti) {
      float s0 = av[0] * in[ti][0];
      float s1 = av[1] * in[ti][1];
      float s2 = av[2] * in[ti][2];
      float s3 = av[3] * in[ti][3];
      #pragma unroll
      for (int v = 4; v < 24; v += 4) {
        s0 = fmaf(av[v],     in[ti][v],     s0);
        s1 = fmaf(av[v + 1], in[ti][v + 1], s1);
        s2 = fmaf(av[v + 2], in[ti][v + 2], s2);
        s3 = fmaf(av[v + 3], in[ti][v + 3], s3);
      }
      s0 = fmaf(av[24], in[ti][24], s0);
      ob[ti * V + u] = (s0 + s1) + (s2 + s3);
    }
  }
}

extern "C" void kernel_launch(void* const* d_in, const int* in_sizes, int n_in,
                              void* d_out, int out_size, void* d_ws, size_t ws_size,
                              hipStream_t stream) {
  (void)in_sizes; (void)n_in; (void)out_size; (void)ws_size;
  const float* x  = (const float*)d_in[0];
  const float* A  = (const float*)d_in[1];
  const float* w1 = (const float*)d_in[2];
  const float* b1 = (const float*)d_in[3];
  const float* w2 = (const float*)d_in[4];
  const float* b2 = (const float*)d_in[5];
  const float* w3 = (const float*)d_in[6];
  const float* b3 = (const float*)d_in[7];
  const float* wr = (const float*)d_in[8];
  const float* br = (const float*)d_in[9];
  float* out = (float*)d_out;
  float* ws  = (float*)d_ws;

  hipLaunchKernelGGL(k1_x12, dim3(NB), dim3(1024), 0, stream,
                     x, w1, b1, w2, b2, ws);
  hipLaunchKernelGGL(k2_fused, dim3(NB, CO / CC), dim3(512), 0, stream,
                     x, A, w3, b3, wr, br, ws, out);
}

// Round 6
// 194.264 us; speedup vs baseline: 1.1356x; 1.1356x over previous
//
#include <hip/hip_runtime.h>
#include <cmath>

namespace {
constexpr int NB  = 256;   // batch
constexpr int CI  = 64;    // in channels
constexpr int CO  = 64;    // out channels
constexpr int TT  = 64;    // time
constexpr int V   = 25;    // vertices
constexpr int REL = 8;     // rel channels
constexpr int TV  = TT * V;   // 1600
constexpr int CC  = 8;     // channels per fused block
constexpr int IP  = 28;    // inp row pad (16B-aligned rows)
constexpr int AP  = 28;    // Af row pad (16B-aligned rows)
}

typedef float f4 __attribute__((ext_vector_type(4)));

// ---------------------------------------------------------------------------
// K1: per-n temporal reduction -> x1,x2 (REL*V each) into ws. (unchanged)
// ---------------------------------------------------------------------------
__global__ __launch_bounds__(1024) void k1_x12(
    const float* __restrict__ x,
    const float* __restrict__ w1, const float* __restrict__ b1,
    const float* __restrict__ w2, const float* __restrict__ b2,
    float* __restrict__ ws) {
  const int n = blockIdx.x;
  const int tid = threadIdx.x;
  __shared__ __align__(16) float xs[8][TV];
  __shared__ float xsum[CI][V];
  __shared__ float w12[2][REL][CI];

  for (int idx = tid; idx < 2 * REL * CI; idx += 1024) {
    int half = idx / (REL * CI), rem = idx % (REL * CI);
    w12[half][rem / CI][rem % CI] = half ? w2[rem] : w1[rem];
  }

  const float4* xb = reinterpret_cast<const float4*>(x + (size_t)n * (CI * TV));
  float4* xsv = reinterpret_cast<float4*>(&xs[0][0]);
  constexpr int V4G = 8 * TV / 4;  // 3200

  for (int g = 0; g < 8; ++g) {
    __syncthreads();
    for (int idx = tid; idx < V4G; idx += 1024)
      xsv[idx] = xb[g * V4G + idx];
    __syncthreads();
    if (tid < 8 * V) {
      int ch = tid / V, v = tid % V;
      float acc = 0.f;
      #pragma unroll
      for (int t = 0; t < TT; ++t) acc += xs[ch][t * V + v];
      xsum[g * 8 + ch][v] = acc;
    }
  }
  __syncthreads();

  if (tid < 2 * REL * V) {
    int half = tid / (REL * V), rem = tid % (REL * V);
    int r = rem / V, v = rem % V;
    float a = 0.f;
    #pragma unroll
    for (int i = 0; i < CI; ++i) a = fmaf(w12[half][r][i], xsum[i][v], a);
    ws[(size_t)n * (2 * REL * V) + tid] = a * (1.f / TT) + (half ? b2[r] : b1[r]);
  }
}

// ---------------------------------------------------------------------------
// K2 fused, swizzled grid: id = [n_hi5][cb3][n_lo3] so all 8 cb-blocks of an
// n are dispatch-adjacent AND on the same XCD (id%8 == n%8) -> x[n] fetched
// into that XCD's L2 once, read 8x.
//   P0: zero LDS pads; Af[8][25][28] (tanh inline, pad cols = 0)
//   P1: inputs[8][64][28] in LDS (400 threads own float4 tv-columns)
//   P2: out[c,t,u] = sum_v Af*inp; 2 t-rows + Af row in NAMED f4 registers
// LDS 81824 B -> 2 blocks/CU.
// ---------------------------------------------------------------------------
__global__ __launch_bounds__(512, 4) void k2_fused(
    const float* __restrict__ x, const float* __restrict__ A,
    const float* __restrict__ w3, const float* __restrict__ b3,
    const float* __restrict__ wr, const float* __restrict__ br,
    const float* __restrict__ ws, float* __restrict__ out) {
  const int id  = blockIdx.x;
  const int n   = (id & 7) | ((id >> 3) & ~7);
  const int cb  = (id >> 3) & 7;
  const int c0  = cb * CC;
  const int tid = threadIdx.x;       // 0..511

  __shared__ __align__(16) float inp[CC * TT * IP];   // 57344 B
  __shared__ __align__(16) float Afs[CC * V * AP];    // 22400 B
  __shared__ __align__(16) float wrs[CI * CC + CC];   // 2080 B (wr^T chunk + br)

  // ---- P0a: zero inp (covers pad columns), stage wr^T chunk (+ br row)
  {
    f4* iz = reinterpret_cast<f4*>(inp);
    #pragma unroll
    for (int k = 0; k < CC * TT * IP / 4 / 512; ++k)   // 7 stores
      iz[tid + k * 512] = (f4)0.f;
    int i = tid >> 3, cc = tid & 7;                    // tid < 512 == CI*CC
    wrs[i * CC + cc] = wr[(size_t)(c0 + cc) * CI + i];
    if (tid < CC) wrs[CI * CC + tid] = br[c0 + tid];
  }

  // ---- P0b: Af[cc][u][v] = A[u][v]+b3[c]+sum_r w3[c][r]*tanh(x1[r][u]-x2[r][v])
  //           pad columns (v>=25) = 0
  const float* x1n = ws + (size_t)n * (2 * REL * V);
  const float* x2n = x1n + REL * V;
  for (int idx = tid; idx < V * AP; idx += 512) {      // 700 tasks
    int u = idx / AP, v = idx % AP;
    if (v < V) {
      float t8[REL];
      #pragma unroll
      for (int r = 0; r < REL; ++r)
        t8[r] = tanhf(x1n[r * V + u] - x2n[r * V + v]);
      const float base = A[u * V + v];
      #pragma unroll
      for (int cc = 0; cc < CC; ++cc) {
        float acc = base + b3[c0 + cc];
        #pragma unroll
        for (int r = 0; r < REL; ++r)
          acc = fmaf(w3[(c0 + cc) * REL + r], t8[r], acc);
        Afs[(cc * V + u) * AP + v] = acc;
      }
    } else {
      #pragma unroll
      for (int cc = 0; cc < CC; ++cc)
        Afs[(cc * V + u) * AP + v] = 0.f;
    }
  }
  __syncthreads();

  // ---- P1: inputs tile (all t) into LDS. 400 threads own float4 tv-columns.
  if (tid < TV / 4) {
    const float* xp = x + (size_t)n * (CI * TV) + tid * 4;
    float acc[CC][4];
    #pragma unroll
    for (int cc = 0; cc < CC; ++cc) {
      float b = wrs[CI * CC + cc];
      acc[cc][0] = b; acc[cc][1] = b; acc[cc][2] = b; acc[cc][3] = b;
    }
    #pragma unroll 4
    for (int i = 0; i < CI; ++i) {
      float4 xv = *reinterpret_cast<const float4*>(xp + (size_t)i * TV);
      float4 wa = *reinterpret_cast<const float4*>(&wrs[i * CC]);      // broadcast
      float4 wb = *reinterpret_cast<const float4*>(&wrs[i * CC + 4]);  // broadcast
      float w8[8] = {wa.x, wa.y, wa.z, wa.w, wb.x, wb.y, wb.z, wb.w};
      #pragma unroll
      for (int cc = 0; cc < CC; ++cc) {
        acc[cc][0] = fmaf(w8[cc], xv.x, acc[cc][0]);
        acc[cc][1] = fmaf(w8[cc], xv.y, acc[cc][1]);
        acc[cc][2] = fmaf(w8[cc], xv.z, acc[cc][2]);
        acc[cc][3] = fmaf(w8[cc], xv.w, acc[cc][3]);
      }
    }
    int tv0 = tid * 4;
    int t = tv0 / V, v = tv0 % V;
    #pragma unroll
    for (int k = 0; k < 4; ++k) {
      #pragma unroll
      for (int cc = 0; cc < CC; ++cc)
        inp[(cc * TT + t) * IP + v] = acc[cc][k];
      if (++v == V) { v = 0; ++t; }
    }
  }
  __syncthreads();

  // ---- P2: thread = (cc, t-pair, u-half); 2 inp rows + Af row in f4 regs
  const int cc = tid >> 6;            // 0..7
  const int tp = (tid >> 1) & 31;     // 0..31
  const int uh = tid & 1;             // 0..1
  const int t0 = tp * 2;

  const f4* r0 = reinterpret_cast<const f4*>(&inp[(cc * TT + t0) * IP]);
  const f4* r1 = reinterpret_cast<const f4*>(&inp[(cc * TT + t0 + 1) * IP]);
  const f4 i0a = r0[0], i0b = r0[1], i0c = r0[2], i0d = r0[3],
           i0e = r0[4], i0f = r0[5], i0g = r0[6];
  const f4 i1a = r1[0], i1b = r1[1], i1c = r1[2], i1d = r1[3],
           i1e = r1[4], i1f = r1[5], i1g = r1[6];

  const float* afbase = &Afs[cc * V * AP];
  float* ob = out + (((size_t)n * CO + (c0 + cc)) * TT + t0) * V;

  const int ubeg = uh ? 13 : 0;
  const int uend = uh ? 25 : 13;
  for (int u = ubeg; u < uend; ++u) {
    const f4* ar = reinterpret_cast<const f4*>(afbase + u * AP);
    const f4 a0 = ar[0], a1 = ar[1], a2 = ar[2], a3 = ar[3],
             a4 = ar[4], a5 = ar[5], a6 = ar[6];   // a6.yzw = 0 pads

    f4 p = a0 * i0a; p += a1 * i0b; p += a2 * i0c; p += a3 * i0d;
    p += a4 * i0e;   p += a5 * i0f; p += a6 * i0g;
    f4 q = a0 * i1a; q += a1 * i1b; q += a2 * i1c; q += a3 * i1d;
    q += a4 * i1e;   q += a5 * i1f; q += a6 * i1g;

    ob[u]     = (p.x + p.y) + (p.z + p.w);
    ob[V + u] = (q.x + q.y) + (q.z + q.w);
  }
}

extern "C" void kernel_launch(void* const* d_in, const int* in_sizes, int n_in,
                              void* d_out, int out_size, void* d_ws, size_t ws_size,
                              hipStream_t stream) {
  (void)in_sizes; (void)n_in; (void)out_size; (void)ws_size;
  const float* x  = (const float*)d_in[0];
  const float* A  = (const float*)d_in[1];
  const float* w1 = (const float*)d_in[2];
  const float* b1 = (const float*)d_in[3];
  const float* w2 = (const float*)d_in[4];
  const float* b2 = (const float*)d_in[5];
  const float* w3 = (const float*)d_in[6];
  const float* b3 = (const float*)d_in[7];
  const float* wr = (const float*)d_in[8];
  const float* br = (const float*)d_in[9];
  float* out = (float*)d_out;
  float* ws  = (float*)d_ws;

  hipLaunchKernelGGL(k1_x12, dim3(NB), dim3(1024), 0, stream,
                     x, w1, b1, w2, b2, ws);
  hipLaunchKernelGGL(k2_fused, dim3(NB * CO / CC), dim3(512), 0, stream,
                     x, A, w3, b3, wr, br, ws, out);
}

// Round 7
// 149.422 us; speedup vs baseline: 1.4763x; 1.3001x over previous
//
#include <hip/hip_runtime.h>
#include <cmath>

namespace {
constexpr int NB  = 256;   // batch
constexpr int CI  = 64;    // in channels
constexpr int CO  = 64;    // out channels
constexpr int TT  = 64;    // time
constexpr int V   = 25;    // vertices
constexpr int REL = 8;     // rel channels
constexpr int TV  = TT * V;   // 1600
constexpr int CC  = 8;     // channels per fused block
constexpr int IP  = 28;    // inp row pad (16B-aligned rows)
constexpr int AP  = 28;    // Af row pad (16B-aligned rows)
}

typedef float f4 __attribute__((ext_vector_type(4)));

// ---------------------------------------------------------------------------
// K1: per-n temporal reduction -> x1,x2 (REL*V each) into ws. (unchanged)
// ---------------------------------------------------------------------------
__global__ __launch_bounds__(1024) void k1_x12(
    const float* __restrict__ x,
    const float* __restrict__ w1, const float* __restrict__ b1,
    const float* __restrict__ w2, const float* __restrict__ b2,
    float* __restrict__ ws) {
  const int n = blockIdx.x;
  const int tid = threadIdx.x;
  __shared__ __align__(16) float xs[8][TV];
  __shared__ float xsum[CI][V];
  __shared__ float w12[2][REL][CI];

  for (int idx = tid; idx < 2 * REL * CI; idx += 1024) {
    int half = idx / (REL * CI), rem = idx % (REL * CI);
    w12[half][rem / CI][rem % CI] = half ? w2[rem] : w1[rem];
  }

  const float4* xb = reinterpret_cast<const float4*>(x + (size_t)n * (CI * TV));
  float4* xsv = reinterpret_cast<float4*>(&xs[0][0]);
  constexpr int V4G = 8 * TV / 4;  // 3200

  for (int g = 0; g < 8; ++g) {
    __syncthreads();
    for (int idx = tid; idx < V4G; idx += 1024)
      xsv[idx] = xb[g * V4G + idx];
    __syncthreads();
    if (tid < 8 * V) {
      int ch = tid / V, v = tid % V;
      float acc = 0.f;
      #pragma unroll
      for (int t = 0; t < TT; ++t) acc += xs[ch][t * V + v];
      xsum[g * 8 + ch][v] = acc;
    }
  }
  __syncthreads();

  if (tid < 2 * REL * V) {
    int half = tid / (REL * V), rem = tid % (REL * V);
    int r = rem / V, v = rem % V;
    float a = 0.f;
    #pragma unroll
    for (int i = 0; i < CI; ++i) a = fmaf(w12[half][r][i], xsum[i][v], a);
    ws[(size_t)n * (2 * REL * V) + tid] = a * (1.f / TT) + (half ? b2[r] : b1[r]);
  }
}

// ---------------------------------------------------------------------------
// K2 fused, swizzled grid: id = [n_hi5][cb3][n_lo3] -> all 8 cb-blocks of an
// n dispatch-adjacent on one XCD; x[n] fetched into L2 once.
//   P0: zero inp pads, stage wr^T; Af[8][25][28] (tanh inline, pad cols 0)
//   P1: inputs[8][64][28] in LDS (400 threads own float4 tv-columns, unroll 8)
//   P2: accumulator form: thread=(cc,tq,uq), acc[4][7] in regs, v-chunk loop
//       with immediate consumption -> minimal LDS reads, no remat incentive.
// LDS 81824 B -> 2 blocks/CU.
// ---------------------------------------------------------------------------
__global__ __launch_bounds__(512, 4) void k2_fused(
    const float* __restrict__ x, const float* __restrict__ A,
    const float* __restrict__ w3, const float* __restrict__ b3,
    const float* __restrict__ wr, const float* __restrict__ br,
    const float* __restrict__ ws, float* __restrict__ out) {
  const int id  = blockIdx.x;
  const int n   = (id & 7) | ((id >> 3) & ~7);
  const int cb  = (id >> 3) & 7;
  const int c0  = cb * CC;
  const int tid = threadIdx.x;       // 0..511

  __shared__ __align__(16) float inp[CC * TT * IP];   // 57344 B
  __shared__ __align__(16) float Afs[CC * V * AP];    // 22400 B
  __shared__ __align__(16) float wrs[CI * CC + CC];   // 2080 B (wr^T chunk + br)

  // ---- P0a: zero inp (pad columns must be 0), stage wr^T chunk (+ br)
  {
    f4* iz = reinterpret_cast<f4*>(inp);
    #pragma unroll
    for (int k = 0; k < CC * TT * IP / 4 / 512; ++k)   // 7 stores
      iz[tid + k * 512] = (f4)0.f;
    int i = tid >> 3, cc = tid & 7;                    // tid < 512 == CI*CC
    wrs[i * CC + cc] = wr[(size_t)(c0 + cc) * CI + i];
    if (tid < CC) wrs[CI * CC + tid] = br[c0 + tid];
  }

  // ---- P0b: Af[cc][u][v] = A[u][v]+b3[c]+sum_r w3[c][r]*tanh(x1[r][u]-x2[r][v])
  //           pad columns (v>=25) = 0 (so f4 chunk 6 is safe)
  const float* x1n = ws + (size_t)n * (2 * REL * V);
  const float* x2n = x1n + REL * V;
  for (int idx = tid; idx < V * AP; idx += 512) {      // 700 tasks
    int u = idx / AP, v = idx % AP;
    if (v < V) {
      float t8[REL];
      #pragma unroll
      for (int r = 0; r < REL; ++r)
        t8[r] = tanhf(x1n[r * V + u] - x2n[r * V + v]);
      const float base = A[u * V + v];
      #pragma unroll
      for (int cc = 0; cc < CC; ++cc) {
        float acc = base + b3[c0 + cc];
        #pragma unroll
        for (int r = 0; r < REL; ++r)
          acc = fmaf(w3[(c0 + cc) * REL + r], t8[r], acc);
        Afs[(cc * V + u) * AP + v] = acc;
      }
    } else {
      #pragma unroll
      for (int cc = 0; cc < CC; ++cc)
        Afs[(cc * V + u) * AP + v] = 0.f;
    }
  }
  __syncthreads();

  // ---- P1: inputs tile (all t) into LDS. 400 threads own float4 tv-columns.
  if (tid < TV / 4) {
    const float* xp = x + (size_t)n * (CI * TV) + tid * 4;
    float acc[CC][4];
    #pragma unroll
    for (int cc = 0; cc < CC; ++cc) {
      float b = wrs[CI * CC + cc];
      acc[cc][0] = b; acc[cc][1] = b; acc[cc][2] = b; acc[cc][3] = b;
    }
    #pragma unroll 8
    for (int i = 0; i < CI; ++i) {
      float4 xv = *reinterpret_cast<const float4*>(xp + (size_t)i * TV);
      float4 wa = *reinterpret_cast<const float4*>(&wrs[i * CC]);      // broadcast
      float4 wb = *reinterpret_cast<const float4*>(&wrs[i * CC + 4]);  // broadcast
      float w8[8] = {wa.x, wa.y, wa.z, wa.w, wb.x, wb.y, wb.z, wb.w};
      #pragma unroll
      for (int cc = 0; cc < CC; ++cc) {
        acc[cc][0] = fmaf(w8[cc], xv.x, acc[cc][0]);
        acc[cc][1] = fmaf(w8[cc], xv.y, acc[cc][1]);
        acc[cc][2] = fmaf(w8[cc], xv.z, acc[cc][2]);
        acc[cc][3] = fmaf(w8[cc], xv.w, acc[cc][3]);
      }
    }
    int tv0 = tid * 4;
    int t = tv0 / V, v = tv0 % V;
    #pragma unroll
    for (int k = 0; k < 4; ++k) {
      #pragma unroll
      for (int cc = 0; cc < CC; ++cc)
        inp[(cc * TT + t) * IP + v] = acc[cc][k];
      if (++v == V) { v = 0; ++t; }
    }
  }
  __syncthreads();

  // ---- P2: thread = (cc, tq, uq). t-rows {tq, tq+16, tq+32, tq+48};
  //      u-rows {6*uq .. 6*uq+6} (overlap at 6/12/18 -> benign dup stores).
  //      acc[4][7] in regs; per v-chunk: 4 inp f4 + 7 Af f4, consumed at once.
  const int cc = tid >> 6;            // 0..7
  const int tq = (tid >> 2) & 15;     // 0..15
  const int uq = tid & 3;             // 0..3
  const int u0 = uq * 6;

  float acc[4][7];
  #pragma unroll
  for (int a = 0; a < 4; ++a)
    #pragma unroll
    for (int b = 0; b < 7; ++b) acc[a][b] = 0.f;

  const float* ib = &inp[(cc * TT + tq) * IP];
  const float* ab = &Afs[(cc * V + u0) * AP];

  #pragma unroll
  for (int chk = 0; chk < 7; ++chk) {
    const f4 x0 = *reinterpret_cast<const f4*>(ib + 0 * 16 * IP + chk * 4);
    const f4 x1 = *reinterpret_cast<const f4*>(ib + 1 * 16 * IP + chk * 4);
    const f4 x2 = *reinterpret_cast<const f4*>(ib + 2 * 16 * IP + chk * 4);
    const f4 x3 = *reinterpret_cast<const f4*>(ib + 3 * 16 * IP + chk * 4);
    #pragma unroll
    for (int ku = 0; ku < 7; ++ku) {
      const f4 a = *reinterpret_cast<const f4*>(ab + ku * AP + chk * 4);
      acc[0][ku] = fmaf(a.w, x0.w, fmaf(a.z, x0.z, fmaf(a.y, x0.y, fmaf(a.x, x0.x, acc[0][ku]))));
      acc[1][ku] = fmaf(a.w, x1.w, fmaf(a.z, x1.z, fmaf(a.y, x1.y, fmaf(a.x, x1.x, acc[1][ku]))));
      acc[2][ku] = fmaf(a.w, x2.w, fmaf(a.z, x2.z, fmaf(a.y, x2.y, fmaf(a.x, x2.x, acc[2][ku]))));
      acc[3][ku] = fmaf(a.w, x3.w, fmaf(a.z, x3.z, fmaf(a.y, x3.y, fmaf(a.x, x3.x, acc[3][ku]))));
    }
  }

  float* ob = out + ((size_t)n * CO + (c0 + cc)) * (TT * V);
  #pragma unroll
  for (int ti = 0; ti < 4; ++ti) {
    const int t = tq + 16 * ti;
    #pragma unroll
    for (int ku = 0; ku < 7; ++ku)
      ob[t * V + u0 + ku] = acc[ti][ku];
  }
}

extern "C" void kernel_launch(void* const* d_in, const int* in_sizes, int n_in,
                              void* d_out, int out_size, void* d_ws, size_t ws_size,
                              hipStream_t stream) {
  (void)in_sizes; (void)n_in; (void)out_size; (void)ws_size;
  const float* x  = (const float*)d_in[0];
  const float* A  = (const float*)d_in[1];
  const float* w1 = (const float*)d_in[2];
  const float* b1 = (const float*)d_in[3];
  const float* w2 = (const float*)d_in[4];
  const float* b2 = (const float*)d_in[5];
  const float* w3 = (const float*)d_in[6];
  const float* b3 = (const float*)d_in[7];
  const float* wr = (const float*)d_in[8];
  const float* br = (const float*)d_in[9];
  float* out = (float*)d_out;
  float* ws  = (float*)d_ws;

  hipLaunchKernelGGL(k1_x12, dim3(NB), dim3(1024), 0, stream,
                     x, w1, b1, w2, b2, ws);
  hipLaunchKernelGGL(k2_fused, dim3(NB * CO / CC), dim3(512), 0, stream,
                     x, A, w3, b3, wr, br, ws, out);
}